// Round 7
// baseline (322.111 us; speedup 1.0000x reference)
//
#include <hip/hip_runtime.h>
#include <hip/hip_bf16.h>

typedef float f32x4 __attribute__((ext_vector_type(4)));
typedef int v8i __attribute__((ext_vector_type(8)));

#define NB 8
#define ND 512
#define NT 2048
#define NCODES 4096
#define NM (NB * NT)
#define MARGIN_F 0.2f
#define ENC_STRIDE 320

// MX fragment image (Zq, Cq), fp8 e4m3:
//   tile (R_, K_) = 128 rows x 128 k = 16 KB at ((R_*4 + K_) * 16384)
//   fragment rg (0..7) = 16 rows x 128 k = 2048 B at rg*2048 within tile
//   bytes [0,1024): lane l's 16 B at l*16 = row rg*16+(l&15), k = (l>>4)*32 + 0..15
//   bytes [1024,2048): same lanes, k = (l>>4)*32 + 16..31

// Map a linear rank to the rank-th SURVIVING tile (tiles of 2^shift rows within each
// batch's valid prefix). Survivor compaction keeps live blocks contiguous in blockIdx.
static __device__ inline bool rank_decode(const int* __restrict__ lengths, int rank,
                                          int shift, int& b, int& tib) {
    int acc = 0;
    bool ok = false;
#pragma unroll
    for (int bb = 0; bb < NB; bb++) {
        int fl = lengths[bb] / ENC_STRIDE;
        int c = (fl + ((1 << shift) - 1)) >> shift;  // ceil(fl / tile_rows)
        if (!ok && rank < acc + c) { b = bb; tib = rank - acc; ok = true; }
        acc += c;
    }
    return ok;
}

// ---- kernel 1: fused prep. blocks [0,1024): student (compacted); [1024,1280): codebook ----
__global__ void prep_fused(const float* __restrict__ sf, const float* __restrict__ cb,
                           const int* __restrict__ lengths,
                           unsigned char* __restrict__ Zq, float* __restrict__ npart,
                           unsigned char* __restrict__ Cq, float* __restrict__ cnorm,
                           float* __restrict__ accum, unsigned int* __restrict__ ticket) {
    __shared__ float tile[128][65];
    __shared__ float redc[4][16];
    const int tid = threadIdx.x;  // 256
    const int wave = tid >> 6, lane = tid & 63, l15 = lane & 15, kq = lane >> 4;

    if (blockIdx.x < 1024) {
        const int bx = blockIdx.x;
        int b, tt;
        if (!rank_decode(lengths, bx >> 2, 6, b, tt)) return;  // 64-row student tiles
        const int t0 = tt * 64;
        const int d0 = (bx & 3) * 128;
        const float* src = sf + (size_t)b * ND * NT;
#pragma unroll
        for (int it = 0; it < 8; it++) {
            int idx = it * 256 + tid;
            int d = idx >> 4, t4 = (idx & 15) * 4;
            float4 v = *(const float4*)(src + (size_t)(d0 + d) * NT + t0 + t4);  // coalesced
            tile[d][t4] = v.x; tile[d][t4 + 1] = v.y; tile[d][t4 + 2] = v.z; tile[d][t4 + 3] = v.w;
        }
        __syncthreads();
        const int m0 = b * NT + t0;
        {
            const int trow = wave * 16 + l15;
            unsigned char q[32];
#pragma unroll
            for (int j = 0; j < 32; j += 2) {
                float a = tile[kq * 32 + j][trow];
                float c = tile[kq * 32 + j + 1][trow];
                int p = __builtin_amdgcn_cvt_pk_fp8_f32(a, c, 0, false);
                q[j] = (unsigned char)(p & 0xFF);
                q[j + 1] = (unsigned char)((p >> 8) & 0xFF);
            }
            const int M_ = m0 >> 7, rg = ((m0 >> 4) & 7) + wave, K_ = d0 >> 7;
            char* base = (char*)Zq + ((size_t)((M_ * 4 + K_) * 8 + rg)) * 2048;
            *(uint4*)(base + lane * 16) = *(uint4*)&q[0];
            *(uint4*)(base + 1024 + lane * 16) = *(uint4*)&q[16];
        }
        if (tid < 64) {
            float s = 0.0f;
#pragma unroll 16
            for (int d = 0; d < 128; d++) {
                float v = tile[d][tid];
                s += v * v;
            }
            npart[(size_t)(d0 >> 7) * NM + m0 + tid] = s;
        }
    } else {
        if (blockIdx.x == 1279 && tid == 0) { *accum = 0.0f; *ticket = 0u; }
        const int r0 = (blockIdx.x - 1024) * 16;
        const int row = r0 + l15;
        const int K_ = wave;  // each wave handles one 128-k quarter
        const float* src = cb + (size_t)row * ND + K_ * 128 + kq * 32;
        unsigned char q[32];
        float s = 0.0f;
#pragma unroll
        for (int j4 = 0; j4 < 8; j4++) {
            float4 v = *(const float4*)(src + j4 * 4);
            s += v.x * v.x + v.y * v.y + v.z * v.z + v.w * v.w;
            int p0 = __builtin_amdgcn_cvt_pk_fp8_f32(v.x, v.y, 0, false);
            int p1 = __builtin_amdgcn_cvt_pk_fp8_f32(v.z, v.w, 0, false);
            q[j4 * 4 + 0] = (unsigned char)(p0 & 0xFF);
            q[j4 * 4 + 1] = (unsigned char)((p0 >> 8) & 0xFF);
            q[j4 * 4 + 2] = (unsigned char)(p1 & 0xFF);
            q[j4 * 4 + 3] = (unsigned char)((p1 >> 8) & 0xFF);
        }
        const int N_ = r0 >> 7, rg = (r0 >> 4) & 7;
        char* base = (char*)Cq + ((size_t)((N_ * 4 + K_) * 8 + rg)) * 2048;
        *(uint4*)(base + lane * 16) = *(uint4*)&q[0];
        *(uint4*)(base + 1024 + lane * 16) = *(uint4*)&q[16];
        s += __shfl_xor(s, 16);
        s += __shfl_xor(s, 32);
        if (lane < 16) redc[wave][l15] = s;
        __syncthreads();
        if (tid < 16) cnorm[r0 + tid] = redc[0][tid] + redc[1][tid] + redc[2][tid] + redc[3][tid];
    }
}

// ---- kernel 2 helpers: register-direct fragment load + 16-MFMA block ----
static __device__ inline v8i ldfrag(const char* p) {
    union { uint4 q[2]; v8i v; } u;
    u.q[0] = *(const uint4*)p;
    u.q[1] = *(const uint4*)(p + 1024);
    return u.v;
}

static __device__ inline void load_frags(const char* gA, const char* gB, int u,
                                         v8i* av, v8i* bv) {
    const char* pA = gA + (size_t)(u & 3) * 16384;
    const char* pB = gB + (size_t)u * 16384;
#pragma unroll
    for (int i = 0; i < 4; i++) av[i] = ldfrag(pA + i * 2048);
#pragma unroll
    for (int i = 0; i < 4; i++) bv[i] = ldfrag(pB + i * 2048);
}

static __device__ inline void mfma16(const v8i* av, const v8i* bv, f32x4 (*acc)[4]) {
#pragma unroll
    for (int mi = 0; mi < 4; mi++)
#pragma unroll
        for (int ni = 0; ni < 4; ni++)
            acc[mi][ni] = __builtin_amdgcn_mfma_scale_f32_16x16x128_f8f6f4(
                av[mi], bv[ni], acc[mi][ni], 0, 0,
                0, 0x7F7F7F7F, 0, 0x7F7F7F7F);  // scales = 1.0 (e8m0 127)
}

// ---- kernel 2: register-direct GEMM, DEPTH-2 REGISTER PIPELINE + XCD co-location ----
// R6 proved all throughput pipes <25% busy with clean codegen: the cost is the
// per-wave serial chain 16 x (16 loads -> ~900cy HBM/L3 latency -> 550cy MFMA),
// because (a) the dynamic kt loop has zero cross-step overlap and (b) blk%8 spread
// the 8 same-M blocks across all 8 XCDs so every A-load missed L2 (FETCH 39.5 MB =
// live-Zq x 8). Fix (a): two explicit fragment reg-sets; loads for step u+1 sit in
// PROGRAM ORDER before step u's MFMAs -> hipcc auto-emits counted vmcnt(16) (its
// documented behavior), loads stay in flight under MFMA, no inline asm, no barriers.
// Live set bounded by construction: 2x64 frag + 64 acc + ~50 misc ~= 249 < 256
// (R5's unroll-4 wanted 4 sets -> spilled). Fix (b): m_rank pinned to blk%8 so all
// 8 nq-blocks of an M-tile share one XCD -> A loads become L2 hits (~250cy).
__global__ __launch_bounds__(256, 2) void triplet_main(
    const unsigned char* __restrict__ Zq, const unsigned char* __restrict__ Cq,
    const float* __restrict__ cnorm, const int* __restrict__ teacher,
    const int* __restrict__ lengths,
    float* __restrict__ negq, float* __restrict__ posq) {
    // XCD co-location decode: blk = 64k + 8*nq + x  ->  m_rank = x + 8k (bijective).
    // All 8 nq-blocks of m_rank share residue x = blk%8 (-> same XCD's L2).
    const int blk = (int)blockIdx.x;
    const int x = blk & 7;
    const int j = blk >> 3;
    const int m_rank = x + 8 * (j >> 3);
    const int nq = j & 7;
    int b, tM;
    if (!rank_decode(lengths, m_rank, 7, b, tM)) return;  // 128-row tiles
    const int M_ = b * 16 + tM;
    const int m0 = M_ * 128;

    const int tid = threadIdx.x;
    const int wave = tid >> 6, lane = tid & 63;
    const int wr = wave >> 1, wc = wave & 1;
    const int l15 = lane & 15, quad = lane >> 4;

    const float INF = __builtin_inff();
    float minv[4][4], posv[4][4];
    int tch[4][4];
#pragma unroll
    for (int mi = 0; mi < 4; mi++)
#pragma unroll
        for (int r = 0; r < 4; r++) {
            minv[mi][r] = INF;
            posv[mi][r] = INF;
            tch[mi][r] = teacher[m0 + wr * 64 + mi * 16 + quad * 4 + r];
        }

    // Per-wave fragment bases into the global fragment images.
    const char* gA = (const char*)Zq + (size_t)(M_ * 4) * 16384 + (wr * 4) * 2048 + lane * 16;
    const char* gB = (const char*)Cq + (size_t)(nq * 16) * 16384 + (wc * 4) * 2048 + lane * 16;

    v8i a0[4], b0[4], a1[4], b1[4];
    load_frags(gA, gB, 0, a0, b0);  // prologue: set0 <- u=0

#pragma unroll 1
    for (int nt = 0; nt < 4; ++nt) {
        const int u0 = nt * 4;
        f32x4 acc[4][4];
#pragma unroll
        for (int mi = 0; mi < 4; mi++)
#pragma unroll
            for (int ni = 0; ni < 4; ni++)
                acc[mi][ni] = (f32x4){0.f, 0.f, 0.f, 0.f};

        // 4 k-steps, sets alternate: u0->set0, u0+1->set1, u0+2->set0, u0+3->set1.
        // Each load block precedes (in program order) the MFMA of the PREVIOUS step,
        // so the compiler's auto-waitcnt before that MFMA is counted, not zero.
        load_frags(gA, gB, u0 + 1, a1, b1);
        mfma16(a0, b0, acc);
        load_frags(gA, gB, u0 + 2, a0, b0);
        mfma16(a1, b1, acc);
        load_frags(gA, gB, u0 + 3, a1, b1);
        mfma16(a0, b0, acc);
        if (nt < 3) load_frags(gA, gB, u0 + 4, a0, b0);  // next nt's set0
        mfma16(a1, b1, acc);

        // fold: running fp32 min of (cnorm - 2*dot); teacher value captured separately
        const int n0 = (nq * 4 + nt) * 128;
        float cn[4]; int col[4];
#pragma unroll
        for (int ni = 0; ni < 4; ni++) {
            col[ni] = n0 + wc * 64 + ni * 16 + l15;
            cn[ni] = cnorm[col[ni]];
        }
#pragma unroll
        for (int mi = 0; mi < 4; mi++)
#pragma unroll
            for (int r = 0; r < 4; r++) {
                int t = tch[mi][r];
#pragma unroll
                for (int ni = 0; ni < 4; ni++) {
                    float val = fmaf(-2.0f, acc[mi][ni][r], cn[ni]);
                    bool ist = (col[ni] == t);
                    minv[mi][r] = fminf(minv[mi][r], ist ? INF : val);
                    posv[mi][r] = fminf(posv[mi][r], ist ? val : INF);
                }
            }
    }

    const int slot = nq * 2 + wc;  // 0..15
#pragma unroll
    for (int mi = 0; mi < 4; mi++)
#pragma unroll
        for (int r = 0; r < 4; r++) {
            float mn = minv[mi][r], ps = posv[mi][r];
#pragma unroll
            for (int off = 1; off < 16; off <<= 1) {
                mn = fminf(mn, __shfl_xor(mn, off));
                ps = fminf(ps, __shfl_xor(ps, off));
            }
            if (l15 == 0) {
                int m = m0 + wr * 64 + mi * 16 + quad * 4 + r;
                negq[(size_t)slot * NM + m] = mn;
                posq[(size_t)slot * NM + m] = ps;
            }
        }
}

// ---- kernel 3: per-row reduce over 16 slots + ticketed finalize (64 blocks only) ----
__global__ void reduce_final(const float* __restrict__ negq, const float* __restrict__ posq,
                             const float* __restrict__ npart, const int* __restrict__ lengths,
                             float* __restrict__ accum, unsigned int* __restrict__ ticket,
                             float* __restrict__ out) {
    const float INF = __builtin_inff();
    const int m = blockIdx.x * 256 + threadIdx.x;
    float mn = INF, ps = INF;
#pragma unroll
    for (int s = 0; s < 16; s++) {
        mn = fminf(mn, negq[(size_t)s * NM + m]);  // coalesced
        ps = fminf(ps, posq[(size_t)s * NM + m]);
    }
    float zn = npart[m] + npart[NM + m] + npart[2 * NM + m] + npart[3 * NM + m];
    float negd = sqrtf(fmaxf(zn + mn, 1e-12f));
    float posd = sqrtf(fmaxf(zn + ps, 1e-12f));
    float tri = fmaxf(posd - negd + MARGIN_F, 0.0f);
    int b = m >> 11;
    int tt = m & (NT - 1);
    int flen = lengths[b] / ENC_STRIDE;
    float val = (tt < flen) ? tri : 0.0f;  // select (not multiply): NaN/garbage-safe

    __shared__ float red[4];
#pragma unroll
    for (int off = 1; off < 64; off <<= 1) val += __shfl_xor(val, off);
    int lane = threadIdx.x & 63, w = threadIdx.x >> 6;
    if (lane == 0) red[w] = val;
    __syncthreads();
    if (threadIdx.x == 0) {
        atomicAdd(accum, red[0] + red[1] + red[2] + red[3]);
        __threadfence();
        unsigned int old = atomicAdd(ticket, 1u);
        if (old == 63u) {  // last block: all adds are visible
            float total = atomicAdd(accum, 0.0f);
            float cnt = 0.0f;
            for (int bb = 0; bb < NB; bb++) cnt += (float)(lengths[bb] / ENC_STRIDE);
            out[0] = total / (cnt + 1e-8f);
        }
    }
}

extern "C" void kernel_launch(void* const* d_in, const int* in_sizes, int n_in,
                              void* d_out, int out_size, void* d_ws, size_t ws_size,
                              hipStream_t stream) {
    const float* sf = (const float*)d_in[0];
    const int* teacher = (const int*)d_in[1];
    const float* cb = (const float*)d_in[2];
    const int* lengths = (const int*)d_in[3];

    char* ws = (char*)d_ws;
    unsigned char* Zq = (unsigned char*)(ws);                  //  8,388,608 B
    unsigned char* Cq = (unsigned char*)(ws + 8388608);        //  2,097,152 B
    float* cnorm = (float*)(ws + 10485760);                    //     16,384 B
    float* npart = (float*)(ws + 10502144);                    //    262,144 B (4 x NM)
    float* negq = (float*)(ws + 10764288);                     //  1,048,576 B (16 x NM)
    float* posq = (float*)(ws + 11812864);                     //  1,048,576 B
    float* accum = (float*)(ws + 12861440);                    //          4 B
    unsigned int* ticket = (unsigned int*)(ws + 12861444);     //          4 B

    prep_fused<<<1280, 256, 0, stream>>>(sf, cb, lengths, Zq, npart, Cq, cnorm, accum, ticket);
    triplet_main<<<1024, 256, 0, stream>>>(Zq, Cq, cnorm, teacher, lengths, negq, posq);
    reduce_final<<<64, 256, 0, stream>>>(negq, posq, npart, lengths, accum, ticket,
                                         (float*)d_out);
}

// Round 8
// 183.082 us; speedup vs baseline: 1.7594x; 1.7594x over previous
//
#include <hip/hip_runtime.h>
#include <hip/hip_bf16.h>

typedef float f32x4 __attribute__((ext_vector_type(4)));
typedef int v8i __attribute__((ext_vector_type(8)));

#define NB 8
#define ND 512
#define NT 2048
#define NCODES 4096
#define NM (NB * NT)
#define MARGIN_F 0.2f
#define ENC_STRIDE 320

// MX fragment image (Zq, Cq), fp8 e4m3:
//   tile (R_, K_) = 128 rows x 128 k = 16 KB at ((R_*4 + K_) * 16384)
//   fragment rg (0..7) = 16 rows x 128 k = 2048 B at rg*2048 within tile
//   bytes [0,1024): lane l's 16 B at l*16 = row rg*16+(l&15), k = (l>>4)*32 + 0..15
//   bytes [1024,2048): same lanes, k = (l>>4)*32 + 16..31

// Map a linear rank to the rank-th SURVIVING tile (tiles of 2^shift rows within each
// batch's valid prefix). Survivor compaction keeps live blocks contiguous in blockIdx.
static __device__ inline bool rank_decode(const int* __restrict__ lengths, int rank,
                                          int shift, int& b, int& tib) {
    int acc = 0;
    bool ok = false;
#pragma unroll
    for (int bb = 0; bb < NB; bb++) {
        int fl = lengths[bb] / ENC_STRIDE;
        int c = (fl + ((1 << shift) - 1)) >> shift;  // ceil(fl / tile_rows)
        if (!ok && rank < acc + c) { b = bb; tib = rank - acc; ok = true; }
        acc += c;
    }
    return ok;
}

// ---- kernel 1: fused prep. blocks [0,1024): student (compacted); [1024,1280): codebook ----
__global__ void prep_fused(const float* __restrict__ sf, const float* __restrict__ cb,
                           const int* __restrict__ lengths,
                           unsigned char* __restrict__ Zq, float* __restrict__ npart,
                           unsigned char* __restrict__ Cq, float* __restrict__ cnorm,
                           float* __restrict__ accum, unsigned int* __restrict__ ticket) {
    __shared__ float tile[128][65];
    __shared__ float redc[4][16];
    const int tid = threadIdx.x;  // 256
    const int wave = tid >> 6, lane = tid & 63, l15 = lane & 15, kq = lane >> 4;

    if (blockIdx.x < 1024) {
        const int bx = blockIdx.x;
        int b, tt;
        if (!rank_decode(lengths, bx >> 2, 6, b, tt)) return;  // 64-row student tiles
        const int t0 = tt * 64;
        const int d0 = (bx & 3) * 128;
        const float* src = sf + (size_t)b * ND * NT;
#pragma unroll
        for (int it = 0; it < 8; it++) {
            int idx = it * 256 + tid;
            int d = idx >> 4, t4 = (idx & 15) * 4;
            float4 v = *(const float4*)(src + (size_t)(d0 + d) * NT + t0 + t4);  // coalesced
            tile[d][t4] = v.x; tile[d][t4 + 1] = v.y; tile[d][t4 + 2] = v.z; tile[d][t4 + 3] = v.w;
        }
        __syncthreads();
        const int m0 = b * NT + t0;
        {
            const int trow = wave * 16 + l15;
            unsigned char q[32];
#pragma unroll
            for (int j = 0; j < 32; j += 2) {
                float a = tile[kq * 32 + j][trow];
                float c = tile[kq * 32 + j + 1][trow];
                int p = __builtin_amdgcn_cvt_pk_fp8_f32(a, c, 0, false);
                q[j] = (unsigned char)(p & 0xFF);
                q[j + 1] = (unsigned char)((p >> 8) & 0xFF);
            }
            const int M_ = m0 >> 7, rg = ((m0 >> 4) & 7) + wave, K_ = d0 >> 7;
            char* base = (char*)Zq + ((size_t)((M_ * 4 + K_) * 8 + rg)) * 2048;
            *(uint4*)(base + lane * 16) = *(uint4*)&q[0];
            *(uint4*)(base + 1024 + lane * 16) = *(uint4*)&q[16];
        }
        if (tid < 64) {
            float s = 0.0f;
#pragma unroll 16
            for (int d = 0; d < 128; d++) {
                float v = tile[d][tid];
                s += v * v;
            }
            npart[(size_t)(d0 >> 7) * NM + m0 + tid] = s;
        }
    } else {
        if (blockIdx.x == 1279 && tid == 0) { *accum = 0.0f; *ticket = 0u; }
        const int r0 = (blockIdx.x - 1024) * 16;
        const int row = r0 + l15;
        const int K_ = wave;  // each wave handles one 128-k quarter
        const float* src = cb + (size_t)row * ND + K_ * 128 + kq * 32;
        unsigned char q[32];
        float s = 0.0f;
#pragma unroll
        for (int j4 = 0; j4 < 8; j4++) {
            float4 v = *(const float4*)(src + j4 * 4);
            s += v.x * v.x + v.y * v.y + v.z * v.z + v.w * v.w;
            int p0 = __builtin_amdgcn_cvt_pk_fp8_f32(v.x, v.y, 0, false);
            int p1 = __builtin_amdgcn_cvt_pk_fp8_f32(v.z, v.w, 0, false);
            q[j4 * 4 + 0] = (unsigned char)(p0 & 0xFF);
            q[j4 * 4 + 1] = (unsigned char)((p0 >> 8) & 0xFF);
            q[j4 * 4 + 2] = (unsigned char)(p1 & 0xFF);
            q[j4 * 4 + 3] = (unsigned char)((p1 >> 8) & 0xFF);
        }
        const int N_ = r0 >> 7, rg = (r0 >> 4) & 7;
        char* base = (char*)Cq + ((size_t)((N_ * 4 + K_) * 8 + rg)) * 2048;
        *(uint4*)(base + lane * 16) = *(uint4*)&q[0];
        *(uint4*)(base + 1024 + lane * 16) = *(uint4*)&q[16];
        s += __shfl_xor(s, 16);
        s += __shfl_xor(s, 32);
        if (lane < 16) redc[wave][l15] = s;
        __syncthreads();
        if (tid < 16) cnorm[r0 + tid] = redc[0][tid] + redc[1][tid] + redc[2][tid] + redc[3][tid];
    }
}

// ---- kernel 2 helpers ----
static __device__ inline v8i ldfrag(const char* p) {
    union { uint4 q[2]; v8i v; } u;
    u.q[0] = *(const uint4*)p;
    u.q[1] = *(const uint4*)(p + 1024);
    return u.v;
}

// per-step fragment set: 2 A-frags + 4 B-frags = 48 VGPR
static __device__ inline void load_frags(const char* gA, const char* gB, int u,
                                         v8i* av, v8i* bv) {
    const char* pA = gA + (size_t)(u & 3) * 16384;
    const char* pB = gB + (size_t)u * 16384;
#pragma unroll
    for (int i = 0; i < 2; i++) av[i] = ldfrag(pA + i * 2048);
#pragma unroll
    for (int i = 0; i < 4; i++) bv[i] = ldfrag(pB + i * 2048);
}

static __device__ inline void mfma8(const v8i* av, const v8i* bv, f32x4 (*acc)[4]) {
#pragma unroll
    for (int mi = 0; mi < 2; mi++)
#pragma unroll
        for (int ni = 0; ni < 4; ni++)
            acc[mi][ni] = __builtin_amdgcn_mfma_scale_f32_16x16x128_f8f6f4(
                av[mi], bv[ni], acc[mi][ni], 0, 0,
                0, 0x7F7F7F7F, 0, 0x7F7F7F7F);  // scales = 1.0 (e8m0 127)
}

// ---- kernel 2: register-direct GEMM, depth-2 pipeline SIZED TO FIT ----
// Register budget law (R2/R3/R5/R7, 4-for-4): per-wave total (VGPR+AGPR, unified
// file) must stay well under 256 (= 512-reg file / 2 waves/SIMD) or hipcc pins arch
// at 128 and spills to scratch (WRITE_SIZE 79-609 MB). R7's acc[4][4] depth-2 needed
// ~260 -> spilled. This round: acc[2][4] (32 AGPR), frag set = 2A+4B = 48 VGPR,
// two sets = 96 -> total ~190. Block = M64 x N512 (4 waves: wr=wave&1 rows 32 each,
// wc=wave>>1 cols 64 each within each nt tile), grid = 256 m-tiles x 8 nq (live
// ~576, ~2 resident/CU). Pipeline: loads for step u+1 precede step u's MFMAs in
// program order -> compiler emits counted vmcnt; pure C++ (R6-style, proven clean),
// no barriers, no LDS, no inline asm.
__global__ __launch_bounds__(256, 2) void triplet_main(
    const unsigned char* __restrict__ Zq, const unsigned char* __restrict__ Cq,
    const float* __restrict__ cnorm, const int* __restrict__ teacher,
    const int* __restrict__ lengths,
    float* __restrict__ negq, float* __restrict__ posq) {
    // XCD co-location: blk = 64k + 8*nq + x -> m_rank = x + 8k; the 8 nq-blocks of
    // one m-tile share residue x (= XCD) so A-frag loads hit that XCD's L2.
    const int blk = (int)blockIdx.x;
    const int x = blk & 7;
    const int j = blk >> 3;
    const int m_rank = x + 8 * (j >> 3);
    const int nq = j & 7;
    int b, tib;
    if (!rank_decode(lengths, m_rank, 6, b, tib)) return;  // 64-row tiles
    const int tg = b * 32 + tib;        // global 64-row tile
    const int m0 = tg * 64;
    const int M_ = tg >> 1;             // 128-row Zq tile
    const int half = tg & 1;            // which 4-frag half of the Zq tile

    const int tid = threadIdx.x;
    const int wave = tid >> 6, lane = tid & 63;
    const int wr = wave & 1, wc = wave >> 1;
    const int l15 = lane & 15, quad = lane >> 4;

    const float INF = __builtin_inff();
    float minv[2][4], posv[2][4];
    int tch[2][4];
    float cn[4][4];
#pragma unroll
    for (int mi = 0; mi < 2; mi++)
#pragma unroll
        for (int r = 0; r < 4; r++) {
            minv[mi][r] = INF;
            posv[mi][r] = INF;
            tch[mi][r] = teacher[m0 + wr * 32 + mi * 16 + quad * 4 + r];
        }
    // preload all cnorm for this block's 512 cols: no global loads inside the loop
#pragma unroll
    for (int nt = 0; nt < 4; nt++)
#pragma unroll
        for (int ni = 0; ni < 4; ni++)
            cn[nt][ni] = cnorm[(nq * 4 + nt) * 128 + wc * 64 + ni * 16 + l15];

    // Per-wave fragment bases.
    // A frag mi of k-tile kt: gA + kt*16384 + mi*2048 (+1024); frags (half*4+wr*2+mi)
    const char* gA = (const char*)Zq + (size_t)(M_ * 4) * 16384 +
                     (size_t)(half * 4 + wr * 2) * 2048 + lane * 16;
    // B frag ni of tile (nt,kt): gB + (nt*4+kt)*16384 + ni*2048 (+1024); frags wc*4+ni
    const char* gB = (const char*)Cq + (size_t)(nq * 16) * 16384 +
                     (size_t)(wc * 4) * 2048 + lane * 16;

    v8i a0[2], b0[4], a1[2], b1[4];
    load_frags(gA, gB, 0, a0, b0);  // prologue: set0 <- u=0

#pragma unroll 1
    for (int nt = 0; nt < 4; ++nt) {
        const int u0 = nt * 4;
        f32x4 acc[2][4];
#pragma unroll
        for (int mi = 0; mi < 2; mi++)
#pragma unroll
            for (int ni = 0; ni < 4; ni++)
                acc[mi][ni] = (f32x4){0.f, 0.f, 0.f, 0.f};

        // loads for step u+1 precede step u's MFMAs -> counted vmcnt, loads in
        // flight under the matrix pipe; sets alternate 0/1/0/1.
        load_frags(gA, gB, u0 + 1, a1, b1);
        mfma8(a0, b0, acc);
        load_frags(gA, gB, u0 + 2, a0, b0);
        mfma8(a1, b1, acc);
        load_frags(gA, gB, u0 + 3, a1, b1);
        mfma8(a0, b0, acc);
        if (nt < 3) load_frags(gA, gB, u0 + 4, a0, b0);  // next nt's set0
        mfma8(a1, b1, acc);

        // fold: running fp32 min of (cnorm - 2*dot); registers only
        const int n0 = (nq * 4 + nt) * 128;
#pragma unroll
        for (int mi = 0; mi < 2; mi++)
#pragma unroll
            for (int r = 0; r < 4; r++) {
                int t = tch[mi][r];
#pragma unroll
                for (int ni = 0; ni < 4; ni++) {
                    float val = fmaf(-2.0f, acc[mi][ni][r], cn[nt][ni]);
                    int colv = n0 + wc * 64 + ni * 16 + l15;
                    bool ist = (colv == t);
                    minv[mi][r] = fminf(minv[mi][r], ist ? INF : val);
                    posv[mi][r] = fminf(posv[mi][r], ist ? val : INF);
                }
            }
    }

    const int slot = nq * 2 + wc;  // 0..15
#pragma unroll
    for (int mi = 0; mi < 2; mi++)
#pragma unroll
        for (int r = 0; r < 4; r++) {
            float mn = minv[mi][r], ps = posv[mi][r];
#pragma unroll
            for (int off = 1; off < 16; off <<= 1) {
                mn = fminf(mn, __shfl_xor(mn, off));
                ps = fminf(ps, __shfl_xor(ps, off));
            }
            if (l15 == 0) {
                int m = m0 + wr * 32 + mi * 16 + quad * 4 + r;
                negq[(size_t)slot * NM + m] = mn;
                posq[(size_t)slot * NM + m] = ps;
            }
        }
}

// ---- kernel 3: per-row reduce over 16 slots + ticketed finalize (64 blocks only) ----
__global__ void reduce_final(const float* __restrict__ negq, const float* __restrict__ posq,
                             const float* __restrict__ npart, const int* __restrict__ lengths,
                             float* __restrict__ accum, unsigned int* __restrict__ ticket,
                             float* __restrict__ out) {
    const float INF = __builtin_inff();
    const int m = blockIdx.x * 256 + threadIdx.x;
    float mn = INF, ps = INF;
#pragma unroll
    for (int s = 0; s < 16; s++) {
        mn = fminf(mn, negq[(size_t)s * NM + m]);  // coalesced
        ps = fminf(ps, posq[(size_t)s * NM + m]);
    }
    float zn = npart[m] + npart[NM + m] + npart[2 * NM + m] + npart[3 * NM + m];
    float negd = sqrtf(fmaxf(zn + mn, 1e-12f));
    float posd = sqrtf(fmaxf(zn + ps, 1e-12f));
    float tri = fmaxf(posd - negd + MARGIN_F, 0.0f);
    int b = m >> 11;
    int tt = m & (NT - 1);
    int flen = lengths[b] / ENC_STRIDE;
    float val = (tt < flen) ? tri : 0.0f;  // select (not multiply): NaN/garbage-safe

    __shared__ float red[4];
#pragma unroll
    for (int off = 1; off < 64; off <<= 1) val += __shfl_xor(val, off);
    int lane = threadIdx.x & 63, w = threadIdx.x >> 6;
    if (lane == 0) red[w] = val;
    __syncthreads();
    if (threadIdx.x == 0) {
        atomicAdd(accum, red[0] + red[1] + red[2] + red[3]);
        __threadfence();
        unsigned int old = atomicAdd(ticket, 1u);
        if (old == 63u) {  // last block: all adds are visible
            float total = atomicAdd(accum, 0.0f);
            float cnt = 0.0f;
            for (int bb = 0; bb < NB; bb++) cnt += (float)(lengths[bb] / ENC_STRIDE);
            out[0] = total / (cnt + 1e-8f);
        }
    }
}

extern "C" void kernel_launch(void* const* d_in, const int* in_sizes, int n_in,
                              void* d_out, int out_size, void* d_ws, size_t ws_size,
                              hipStream_t stream) {
    const float* sf = (const float*)d_in[0];
    const int* teacher = (const int*)d_in[1];
    const float* cb = (const float*)d_in[2];
    const int* lengths = (const int*)d_in[3];

    char* ws = (char*)d_ws;
    unsigned char* Zq = (unsigned char*)(ws);                  //  8,388,608 B
    unsigned char* Cq = (unsigned char*)(ws + 8388608);        //  2,097,152 B
    float* cnorm = (float*)(ws + 10485760);                    //     16,384 B
    float* npart = (float*)(ws + 10502144);                    //    262,144 B (4 x NM)
    float* negq = (float*)(ws + 10764288);                     //  1,048,576 B (16 x NM)
    float* posq = (float*)(ws + 11812864);                     //  1,048,576 B
    float* accum = (float*)(ws + 12861440);                    //          4 B
    unsigned int* ticket = (unsigned int*)(ws + 12861444);     //          4 B

    prep_fused<<<1280, 256, 0, stream>>>(sf, cb, lengths, Zq, npart, Cq, cnorm, accum, ticket);
    triplet_main<<<2048, 256, 0, stream>>>(Zq, Cq, cnorm, teacher, lengths, negq, posq);
    reduce_final<<<64, 256, 0, stream>>>(negq, posq, npart, lengths, accum, ticket,
                                         (float*)d_out);
}

// Round 9
// 129.083 us; speedup vs baseline: 2.4954x; 1.4183x over previous
//
#include <hip/hip_runtime.h>
#include <hip/hip_bf16.h>

typedef float f32x4 __attribute__((ext_vector_type(4)));
typedef int v8i __attribute__((ext_vector_type(8)));

#define NB 8
#define ND 512
#define NT 2048
#define NCODES 4096
#define NM (NB * NT)
#define MARGIN_F 0.2f
#define ENC_STRIDE 320

// MX fragment image (Zq, Cq), fp8 e4m3:
//   tile (R_, K_) = 128 rows x 128 k = 16 KB at ((R_*4 + K_) * 16384)
//   fragment rg (0..7) = 16 rows x 128 k = 2048 B at rg*2048 within tile
//   bytes [0,1024): lane l's 16 B at l*16 = row rg*16+(l&15), k = (l>>4)*32 + 0..15
//   bytes [1024,2048): same lanes, k = (l>>4)*32 + 16..31

// Map a linear rank to the rank-th SURVIVING tile (tiles of 2^shift rows within each
// batch's valid prefix). Survivor compaction keeps live blocks contiguous in blockIdx.
static __device__ inline bool rank_decode(const int* __restrict__ lengths, int rank,
                                          int shift, int& b, int& tib) {
    int acc = 0;
    bool ok = false;
#pragma unroll
    for (int bb = 0; bb < NB; bb++) {
        int fl = lengths[bb] / ENC_STRIDE;
        int c = (fl + ((1 << shift) - 1)) >> shift;  // ceil(fl / tile_rows)
        if (!ok && rank < acc + c) { b = bb; tib = rank - acc; ok = true; }
        acc += c;
    }
    return ok;
}

// ---- kernel 1: fused prep. blocks [0,1024): student (compacted); [1024,1280): codebook ----
__global__ void prep_fused(const float* __restrict__ sf, const float* __restrict__ cb,
                           const int* __restrict__ lengths,
                           unsigned char* __restrict__ Zq, float* __restrict__ npart,
                           unsigned char* __restrict__ Cq, float* __restrict__ cnorm,
                           float* __restrict__ accum, unsigned int* __restrict__ ticket) {
    __shared__ float tile[128][65];
    __shared__ float redc[4][16];
    const int tid = threadIdx.x;  // 256
    const int wave = tid >> 6, lane = tid & 63, l15 = lane & 15, kq = lane >> 4;

    if (blockIdx.x < 1024) {
        const int bx = blockIdx.x;
        int b, tt;
        if (!rank_decode(lengths, bx >> 2, 6, b, tt)) return;  // 64-row student tiles
        const int t0 = tt * 64;
        const int d0 = (bx & 3) * 128;
        const float* src = sf + (size_t)b * ND * NT;
#pragma unroll
        for (int it = 0; it < 8; it++) {
            int idx = it * 256 + tid;
            int d = idx >> 4, t4 = (idx & 15) * 4;
            float4 v = *(const float4*)(src + (size_t)(d0 + d) * NT + t0 + t4);  // coalesced
            tile[d][t4] = v.x; tile[d][t4 + 1] = v.y; tile[d][t4 + 2] = v.z; tile[d][t4 + 3] = v.w;
        }
        __syncthreads();
        const int m0 = b * NT + t0;
        {
            const int trow = wave * 16 + l15;
            unsigned char q[32];
#pragma unroll
            for (int j = 0; j < 32; j += 2) {
                float a = tile[kq * 32 + j][trow];
                float c = tile[kq * 32 + j + 1][trow];
                int p = __builtin_amdgcn_cvt_pk_fp8_f32(a, c, 0, false);
                q[j] = (unsigned char)(p & 0xFF);
                q[j + 1] = (unsigned char)((p >> 8) & 0xFF);
            }
            const int M_ = m0 >> 7, rg = ((m0 >> 4) & 7) + wave, K_ = d0 >> 7;
            char* base = (char*)Zq + ((size_t)((M_ * 4 + K_) * 8 + rg)) * 2048;
            *(uint4*)(base + lane * 16) = *(uint4*)&q[0];
            *(uint4*)(base + 1024 + lane * 16) = *(uint4*)&q[16];
        }
        if (tid < 64) {
            float s = 0.0f;
#pragma unroll 16
            for (int d = 0; d < 128; d++) {
                float v = tile[d][tid];
                s += v * v;
            }
            npart[(size_t)(d0 >> 7) * NM + m0 + tid] = s;
        }
    } else {
        if (blockIdx.x == 1279 && tid == 0) { *accum = 0.0f; *ticket = 0u; }
        const int r0 = (blockIdx.x - 1024) * 16;
        const int row = r0 + l15;
        const int K_ = wave;  // each wave handles one 128-k quarter
        const float* src = cb + (size_t)row * ND + K_ * 128 + kq * 32;
        unsigned char q[32];
        float s = 0.0f;
#pragma unroll
        for (int j4 = 0; j4 < 8; j4++) {
            float4 v = *(const float4*)(src + j4 * 4);
            s += v.x * v.x + v.y * v.y + v.z * v.z + v.w * v.w;
            int p0 = __builtin_amdgcn_cvt_pk_fp8_f32(v.x, v.y, 0, false);
            int p1 = __builtin_amdgcn_cvt_pk_fp8_f32(v.z, v.w, 0, false);
            q[j4 * 4 + 0] = (unsigned char)(p0 & 0xFF);
            q[j4 * 4 + 1] = (unsigned char)((p0 >> 8) & 0xFF);
            q[j4 * 4 + 2] = (unsigned char)(p1 & 0xFF);
            q[j4 * 4 + 3] = (unsigned char)((p1 >> 8) & 0xFF);
        }
        const int N_ = r0 >> 7, rg = (r0 >> 4) & 7;
        char* base = (char*)Cq + ((size_t)((N_ * 4 + K_) * 8 + rg)) * 2048;
        *(uint4*)(base + lane * 16) = *(uint4*)&q[0];
        *(uint4*)(base + 1024 + lane * 16) = *(uint4*)&q[16];
        s += __shfl_xor(s, 16);
        s += __shfl_xor(s, 32);
        if (lane < 16) redc[wave][l15] = s;
        __syncthreads();
        if (tid < 16) cnorm[r0 + tid] = redc[0][tid] + redc[1][tid] + redc[2][tid] + redc[3][tid];
    }
}

// ---- kernel 2 helpers (R6-proven codegen) ----
static __device__ inline v8i ldfrag(const char* p) {
    union { uint4 q[2]; v8i v; } u;
    u.q[0] = *(const uint4*)p;
    u.q[1] = *(const uint4*)(p + 1024);
    return u.v;
}

// ---- kernel 2: register-direct GEMM, ONE 128x128 TILE PER BLOCK (4 k-steps) ----
// Clean-run record (R0/R1/R4/R6 all 52 us): MFMA busy = 8.8 us = exactly the math;
// waves starve 83% of the time, occupancy grid-limited at ~544 live blocks. Every
// register-pipeline attempt spilled (R2/R3/R5/R7/R8 - hipcc SSA-renames multi-set
// buffers into >240 live regs). Spill-proof fix: keep R6's exact serial step (single
// frag set, dynamic k-loop, 88 VGPR) and DELETE the nt loop - each block now does one
// 128x128 output tile (4 k-steps), grid 4096, live blocks ~2176 (4x concurrency,
// 1/4 chain length). Fold moved AFTER the k-loop (full dot available) - smaller
// in-loop live set than R6. Cross-wc column-min via 2KB LDS epilogue -> 32 slots.
// XCD co-location: same-m blocks share blk%8 so the A-tile stays L2-local.
__global__ __launch_bounds__(256, 2) void triplet_main(
    const unsigned char* __restrict__ Zq, const unsigned char* __restrict__ Cq,
    const float* __restrict__ cnorm, const int* __restrict__ teacher,
    const int* __restrict__ lengths,
    float* __restrict__ negq, float* __restrict__ posq) {
    __shared__ float smn[2][64], smp[2][64];

    // decode: blk = x + 8*(N_ + 32*k); m_rank = x + 8k. The 32 N_-blocks of one
    // m-tile share residue x (= XCD) -> A-tile (64 KB) L2-resident.
    const int blk = (int)blockIdx.x;
    const int x = blk & 7;
    const int rest = blk >> 3;
    const int N_ = rest & 31;   // 128-col codebook tile
    const int kk = rest >> 5;   // 0..15
    const int m_rank = x + 8 * kk;
    int b, tM;
    if (!rank_decode(lengths, m_rank, 7, b, tM)) return;  // 128-row tiles
    const int M_ = b * 16 + tM;
    const int m0 = M_ * 128;

    const int tid = threadIdx.x;
    const int wave = tid >> 6, lane = tid & 63;
    const int wr = wave >> 1, wc = wave & 1;
    const int l15 = lane & 15, quad = lane >> 4;

    const float INF = __builtin_inff();
    int tch[4][4];
#pragma unroll
    for (int mi = 0; mi < 4; mi++)
#pragma unroll
        for (int r = 0; r < 4; r++)
            tch[mi][r] = teacher[m0 + wr * 64 + mi * 16 + quad * 4 + r];

    // Per-wave fragment bases (A: rows wr*64.., B: cols wc*64.. of tile N_).
    const char* gA = (const char*)Zq + (size_t)(M_ * 4) * 16384 +
                     (size_t)(wr * 4) * 2048 + lane * 16;
    const char* gB = (const char*)Cq + (size_t)(N_ * 4) * 16384 +
                     (size_t)(wc * 4) * 2048 + lane * 16;

    f32x4 acc[4][4];
#pragma unroll
    for (int mi = 0; mi < 4; mi++)
#pragma unroll
        for (int ni = 0; ni < 4; ni++)
            acc[mi][ni] = (f32x4){0.f, 0.f, 0.f, 0.f};

#pragma unroll 1  // dynamic: single frag set live (R6's proven 88-VGPR codegen)
    for (int kt = 0; kt < 4; ++kt) {
        const char* pA = gA + (size_t)kt * 16384;
        const char* pB = gB + (size_t)kt * 16384;
        v8i av[4], bv[4];
#pragma unroll
        for (int mi = 0; mi < 4; mi++) av[mi] = ldfrag(pA + mi * 2048);
#pragma unroll
        for (int ni = 0; ni < 4; ni++) bv[ni] = ldfrag(pB + ni * 2048);
#pragma unroll
        for (int mi = 0; mi < 4; mi++)
#pragma unroll
            for (int ni = 0; ni < 4; ni++)
                acc[mi][ni] = __builtin_amdgcn_mfma_scale_f32_16x16x128_f8f6f4(
                    av[mi], bv[ni], acc[mi][ni], 0, 0,
                    0, 0x7F7F7F7F, 0, 0x7F7F7F7F);  // scales = 1.0 (e8m0 127)
    }

    // ---- fold (full K done): per-row min over this wave's 64 cols ----
    const int n0 = N_ * 128;
    float cn[4]; int col[4];
#pragma unroll
    for (int ni = 0; ni < 4; ni++) {
        col[ni] = n0 + wc * 64 + ni * 16 + l15;
        cn[ni] = cnorm[col[ni]];
    }
    float rmn[4][4], rps[4][4];
#pragma unroll
    for (int mi = 0; mi < 4; mi++)
#pragma unroll
        for (int r = 0; r < 4; r++) {
            int t = tch[mi][r];
            float mn = INF, ps = INF;
#pragma unroll
            for (int ni = 0; ni < 4; ni++) {
                float val = fmaf(-2.0f, acc[mi][ni][r], cn[ni]);
                bool ist = (col[ni] == t);
                mn = fminf(mn, ist ? INF : val);
                ps = fminf(ps, ist ? val : INF);
            }
#pragma unroll
            for (int off = 1; off < 16; off <<= 1) {
                mn = fminf(mn, __shfl_xor(mn, off));
                ps = fminf(ps, __shfl_xor(ps, off));
            }
            rmn[mi][r] = mn;  // valid on lanes with l15==0
            rps[mi][r] = ps;
        }

    // ---- cross-wc combine via LDS, then one global write per row ----
    if (wc == 1 && l15 == 0) {
#pragma unroll
        for (int mi = 0; mi < 4; mi++)
#pragma unroll
            for (int r = 0; r < 4; r++) {
                smn[wr][mi * 16 + quad * 4 + r] = rmn[mi][r];
                smp[wr][mi * 16 + quad * 4 + r] = rps[mi][r];
            }
    }
    __syncthreads();
    if (wc == 0 && l15 == 0) {
#pragma unroll
        for (int mi = 0; mi < 4; mi++)
#pragma unroll
            for (int r = 0; r < 4; r++) {
                int rl = mi * 16 + quad * 4 + r;
                float mn = fminf(rmn[mi][r], smn[wr][rl]);
                float ps = fminf(rps[mi][r], smp[wr][rl]);
                int m = m0 + wr * 64 + rl;
                negq[(size_t)N_ * NM + m] = mn;
                posq[(size_t)N_ * NM + m] = ps;
            }
    }
}

// ---- kernel 3: per-row reduce over 32 slots + ticketed finalize (64 blocks only) ----
__global__ void reduce_final(const float* __restrict__ negq, const float* __restrict__ posq,
                             const float* __restrict__ npart, const int* __restrict__ lengths,
                             float* __restrict__ accum, unsigned int* __restrict__ ticket,
                             float* __restrict__ out) {
    const float INF = __builtin_inff();
    const int m = blockIdx.x * 256 + threadIdx.x;
    float mn = INF, ps = INF;
#pragma unroll 8
    for (int s = 0; s < 32; s++) {
        mn = fminf(mn, negq[(size_t)s * NM + m]);  // coalesced
        ps = fminf(ps, posq[(size_t)s * NM + m]);
    }
    float zn = npart[m] + npart[NM + m] + npart[2 * NM + m] + npart[3 * NM + m];
    float negd = sqrtf(fmaxf(zn + mn, 1e-12f));
    float posd = sqrtf(fmaxf(zn + ps, 1e-12f));
    float tri = fmaxf(posd - negd + MARGIN_F, 0.0f);
    int b = m >> 11;
    int tt = m & (NT - 1);
    int flen = lengths[b] / ENC_STRIDE;
    float val = (tt < flen) ? tri : 0.0f;  // select (not multiply): NaN/garbage-safe

    __shared__ float red[4];
#pragma unroll
    for (int off = 1; off < 64; off <<= 1) val += __shfl_xor(val, off);
    int lane = threadIdx.x & 63, w = threadIdx.x >> 6;
    if (lane == 0) red[w] = val;
    __syncthreads();
    if (threadIdx.x == 0) {
        atomicAdd(accum, red[0] + red[1] + red[2] + red[3]);
        __threadfence();
        unsigned int old = atomicAdd(ticket, 1u);
        if (old == 63u) {  // last block: all adds are visible
            float total = atomicAdd(accum, 0.0f);
            float cnt = 0.0f;
            for (int bb = 0; bb < NB; bb++) cnt += (float)(lengths[bb] / ENC_STRIDE);
            out[0] = total / (cnt + 1e-8f);
        }
    }
}

extern "C" void kernel_launch(void* const* d_in, const int* in_sizes, int n_in,
                              void* d_out, int out_size, void* d_ws, size_t ws_size,
                              hipStream_t stream) {
    const float* sf = (const float*)d_in[0];
    const int* teacher = (const int*)d_in[1];
    const float* cb = (const float*)d_in[2];
    const int* lengths = (const int*)d_in[3];

    char* ws = (char*)d_ws;
    unsigned char* Zq = (unsigned char*)(ws);                  //  8,388,608 B
    unsigned char* Cq = (unsigned char*)(ws + 8388608);        //  2,097,152 B
    float* cnorm = (float*)(ws + 10485760);                    //     16,384 B
    float* npart = (float*)(ws + 10502144);                    //    262,144 B (4 x NM)
    float* negq = (float*)(ws + 10764288);                     //  2,097,152 B (32 x NM)
    float* posq = (float*)(ws + 12861440);                     //  2,097,152 B
    float* accum = (float*)(ws + 14958592);                    //          4 B
    unsigned int* ticket = (unsigned int*)(ws + 14958596);     //          4 B

    prep_fused<<<1280, 256, 0, stream>>>(sf, cb, lengths, Zq, npart, Cq, cnorm, accum, ticket);
    triplet_main<<<4096, 256, 0, stream>>>(Zq, Cq, cnorm, teacher, lengths, negq, posq);
    reduce_final<<<64, 256, 0, stream>>>(negq, posq, npart, lengths, accum, ticket,
                                         (float*)d_out);
}